// Round 16
// baseline (289.883 us; speedup 1.0000x reference)
//
#include <hip/hip_runtime.h>

#define NN 100000
#define EE 1600000
#define NBUCK ((NN + 255) >> 8)        // 391
#define CHUNK 8192
#define NPBLK ((EE + CHUNK - 1) / CHUNK) // 196

typedef __attribute__((ext_vector_type(8))) short short8_t;
typedef __attribute__((ext_vector_type(4))) short short4_t;
typedef __attribute__((ext_vector_type(4))) float f32x4;

static __device__ inline unsigned short f2bf(float f) {
    unsigned int u = __float_as_uint(f);
    u += 0x7FFFu + ((u >> 16) & 1u);
    return (unsigned short)(u >> 16);
}
static __device__ inline float bf2f(unsigned short h) {
    return __uint_as_float(((unsigned int)h) << 16);
}
static __device__ inline float u2f(unsigned int u) { return __uint_as_float(u); }

// ================= CSR bodies =================
static __device__ void part_count_body(int bid, int* h, const int* __restrict__ ei,
                                       int* __restrict__ cnt) {
    for (int i = threadIdx.x; i < NBUCK; i += 256) h[i] = 0;
    __syncthreads();
    int e0 = bid * CHUNK;
    int e1 = e0 + CHUNK; if (e1 > EE) e1 = EE;
    for (int e = e0 + threadIdx.x; e < e1; e += 256)
        atomicAdd(&h[ei[EE + e] >> 8], 1);
    __syncthreads();
    for (int i = threadIdx.x; i < NBUCK; i += 256)
        cnt[bid * NBUCK + i] = h[i];
}

static __device__ void part_scan_body(int* S, const int* __restrict__ cnt,
                                      int* __restrict__ base, int* __restrict__ bbase) {
    int* A = S;
    int* B = S + 512;
    int t = threadIdx.x;
    int totLoc[2];
#pragma unroll
    for (int q = 0; q < 2; ++q) {
        int idx = t + q * 256;
        int v = 0;
        if (idx < NBUCK)
            for (int k = 0; k < NPBLK; ++k) v += cnt[k * NBUCK + idx];
        totLoc[q] = v;
        A[idx] = v;
    }
    __syncthreads();
    int* src = A;
    int* dst = B;
    for (int off = 1; off < 512; off <<= 1) {
#pragma unroll
        for (int q = 0; q < 2; ++q) {
            int idx = t + q * 256;
            dst[idx] = src[idx] + (idx >= off ? src[idx - off] : 0);
        }
        __syncthreads();
        int* tmp = src; src = dst; dst = tmp;
    }
#pragma unroll
    for (int q = 0; q < 2; ++q) {
        int idx = t + q * 256;
        if (idx < NBUCK) {
            int excl = src[idx] - totLoc[q];
            bbase[idx] = excl;
            int run = excl;
            for (int k = 0; k < NPBLK; ++k) {
                base[k * NBUCK + idx] = run;
                run += cnt[k * NBUCK + idx];
            }
        }
    }
    if (t == 0) bbase[NBUCK] = EE;
}

static __device__ void part_scatter_body(int bid, int* lcur, const int* __restrict__ ei,
                                         const int* __restrict__ base,
                                         unsigned int* __restrict__ bbuf) {
    for (int i = threadIdx.x; i < NBUCK; i += 256)
        lcur[i] = base[bid * NBUCK + i];
    __syncthreads();
    int e0 = bid * CHUNK;
    int e1 = e0 + CHUNK; if (e1 > EE) e1 = EE;
    for (int e = e0 + threadIdx.x; e < e1; e += 256) {
        int s = ei[e], d = ei[EE + e];
        int pos = atomicAdd(&lcur[d >> 8], 1);
        bbuf[pos] = (unsigned int)s | ((unsigned int)(d & 255) << 24);
    }
}

static __device__ void csr_build_body(int b, int* S, const unsigned int* __restrict__ bbuf,
                                      const int* __restrict__ bbase,
                                      int* __restrict__ row_ptr, int* __restrict__ col) {
    int* hist = S;
    int* sc   = S + 256;
    int* lcur = S + 512;
    int t = threadIdx.x;
    int n0 = b << 8;
    int nCnt = NN - n0; if (nCnt > 256) nCnt = 256;
    int es = bbase[b], ee2 = bbase[b + 1];
    hist[t] = 0;
    __syncthreads();
    for (int i = es + t; i < ee2; i += 256)
        atomicAdd(&hist[bbuf[i] >> 24], 1);
    __syncthreads();
    int v = hist[t];
    sc[t] = v;
    __syncthreads();
    for (int off = 1; off < 256; off <<= 1) {
        int u = (t >= off) ? sc[t - off] : 0;
        __syncthreads();
        sc[t] += u;
        __syncthreads();
    }
    int excl = sc[t] - v;
    if (t < nCnt) row_ptr[n0 + t] = es + excl;
    if (b == 0 && t == 0) row_ptr[NN] = EE;
    lcur[t] = excl;
    __syncthreads();
    for (int i = es + t; i < ee2; i += 256) {
        unsigned int pk = bbuf[i];
        int lpos = atomicAdd(&lcur[pk >> 24], 1);
        col[es + lpos] = (int)(pk & 0x00FFFFFFu);
    }
}

// ================= weight prep bodies =================
static __device__ void bsplit_body(int col, const float* __restrict__ W, int ldw, int K, int N,
                                   unsigned short* __restrict__ BThi,
                                   unsigned short* __restrict__ BTlo,
                                   int stride, int koff, int KPseg) {
    int k = threadIdx.x;
    if (k >= KPseg) return;
    float v = (k < K && col < N) ? W[(size_t)k * ldw + col] : 0.f;
    unsigned short hi = f2bf(v);
    unsigned short lo = f2bf(v - bf2f(hi));
    BThi[(size_t)col * stride + koff + k] = hi;
    BTlo[(size_t)col * stride + koff + k] = lo;
}

static __device__ void cvec_body(const float* __restrict__ b_feat,
                                 const float* __restrict__ W0, float* __restrict__ cvec) {
    int j = threadIdx.x;
    if (j >= 128) return;
    float s = 0.f;
    for (int k = 0; k < 128; ++k) s += b_feat[k] * W0[(40 + k) * 128 + j];
    cvec[j] = s;
}

// ======== MFMA GEMM device body (R12 loop; used by prep2 + K4) ========
template <int OUTBF16, int AMODE, int ATTN, int NCT>
static __device__ void gemm_body(int gbid, unsigned short* lds,
    const void* __restrict__ A1v, int lda1, int K1, int KP1,
    const float* __restrict__ A2, int lda2, int K2,
    int M,
    const unsigned short* __restrict__ BThi, const unsigned short* __restrict__ BTlo,
    int bstride, int KPtot,
    void* __restrict__ Cout, int ldc, int Nact, const float* __restrict__ bias,
    const float* __restrict__ att_src, const float* __restrict__ att_dst,
    float* __restrict__ a_srcO, float* __restrict__ a_dstO)
{
    constexpr int ASZ = (AMODE == 0) ? 4096 : 2048;
    constexpr int BHALF = (NCT == 4) ? 4096 : 2048;
    constexpr int BHI_OFF = ASZ;
    constexpr int BLO_OFF = ASZ + BHALF;

    const int t = threadIdx.x;
    const int w = t >> 6, lane = t & 63;
    const int row0 = gbid * 64;
    const int rbase = (w & 1) * 32;
    const int cbase = (NCT == 4) ? (w >> 1) * 64 : (w >> 1) * 32;

    f32x4 acc[2][NCT];
#pragma unroll
    for (int i = 0; i < 2; ++i)
#pragma unroll
        for (int j = 0; j < NCT; ++j) acc[i][j] = (f32x4){0.f, 0.f, 0.f, 0.f};

    const int arow = t >> 2;
    const int aslot = t & 3;
    const bool rowok = (row0 + arow) < M;
    const int aoff = arow * 32 + (((aslot ^ ((arow >> 1) & 3))) << 3);

    const int bc0 = t >> 2,         bs0 = t & 3;
    const int bc1 = (t + 256) >> 2, bs1 = (t + 256) & 3;
    const int bo0 = bc0 * 32 + ((bs0 ^ ((bc0 >> 1) & 3)) << 3);
    const int bo1 = bc1 * 32 + ((bs1 ^ ((bc1 >> 1) & 3)) << 3);

    float ra[8];
    short8_t rab;
    short8_t rbh0, rbl0, rbh1, rbl1;
    const short8_t zz = {0, 0, 0, 0, 0, 0, 0, 0};

#define LOADB_(k0_) {                                                     \
        size_t g0_ = (size_t)bc0 * bstride + (k0_) + bs0 * 8;             \
        rbh0 = *(const short8_t*)&BThi[g0_];                              \
        rbl0 = *(const short8_t*)&BTlo[g0_];                              \
        if (NCT == 4) {                                                   \
            size_t g1_ = (size_t)bc1 * bstride + (k0_) + bs1 * 8;         \
            rbh1 = *(const short8_t*)&BThi[g1_];                          \
            rbl1 = *(const short8_t*)&BTlo[g1_];                          \
        }                                                                 \
    }

#define LOADA_(k0_) {                                                     \
        if (AMODE == 1) {                                                 \
            int gk = (k0_) + aslot * 8;                                   \
            if (rowok && gk + 8 <= K1) {                                  \
                const unsigned short* Ab =                                \
                    (const unsigned short*)A1v + (size_t)(row0 + arow) * lda1; \
                rab = *(const short8_t*)&Ab[gk];                          \
            } else rab = zz;                                              \
        } else {                                                          \
            const float* Asrc; int gk, Klim;                              \
            if ((k0_) < KP1) {                                            \
                Asrc = (const float*)A1v + (size_t)(row0 + arow) * lda1;  \
                gk = (k0_) + aslot * 8; Klim = K1;                        \
            } else {                                                      \
                Asrc = A2 + (size_t)(row0 + arow) * lda2;                 \
                gk = (k0_) - KP1 + aslot * 8; Klim = K2;                  \
            }                                                             \
            if (rowok && gk + 8 <= Klim) {                                \
                float4 v0 = *(const float4*)(Asrc + gk);                  \
                float4 v1 = *(const float4*)(Asrc + gk + 4);              \
                ra[0] = v0.x; ra[1] = v0.y; ra[2] = v0.z; ra[3] = v0.w;   \
                ra[4] = v1.x; ra[5] = v1.y; ra[6] = v1.z; ra[7] = v1.w;   \
            } else {                                                      \
                for (int j_ = 0; j_ < 8; ++j_) ra[j_] = 0.f;              \
            }                                                             \
        }                                                                 \
    }

    LOADA_(0);
    LOADB_(0);

    for (int k0 = 0; k0 < KPtot; k0 += 32) {
        if (AMODE == 1) {
            *(short8_t*)&lds[aoff] = rab;
        } else if (AMODE == 2) {
            short8_t vh;
#pragma unroll
            for (int j = 0; j < 8; ++j) vh[j] = (short)f2bf(ra[j]);
            *(short8_t*)&lds[aoff] = vh;
        } else {
            short8_t vh, vl;
#pragma unroll
            for (int j = 0; j < 8; ++j) {
                unsigned short hi = f2bf(ra[j]);
                vh[j] = (short)hi;
                vl[j] = (short)f2bf(ra[j] - bf2f(hi));
            }
            *(short8_t*)&lds[aoff] = vh;
            *(short8_t*)&lds[2048 + aoff] = vl;
        }
        *(short8_t*)&lds[BHI_OFF + bo0] = rbh0;
        *(short8_t*)&lds[BLO_OFF + bo0] = rbl0;
        if (NCT == 4) {
            *(short8_t*)&lds[BHI_OFF + bo1] = rbh1;
            *(short8_t*)&lds[BLO_OFF + bo1] = rbl1;
        }
        __syncthreads();

        if (k0 + 32 < KPtot) {
            LOADA_(k0 + 32);
            LOADB_(k0 + 32);
        }

        short8_t Ah[2], Al[2], Bh[NCT], Bl[NCT];
        const int fslot = lane >> 4;
#pragma unroll
        for (int rt = 0; rt < 2; ++rt) {
            int r = rbase + rt * 16 + (lane & 15);
            int off = r * 32 + ((fslot ^ ((r >> 1) & 3)) << 3);
            Ah[rt] = *(const short8_t*)&lds[off];
            if (AMODE == 0) Al[rt] = *(const short8_t*)&lds[2048 + off];
        }
#pragma unroll
        for (int ct = 0; ct < NCT; ++ct) {
            int c = cbase + ct * 16 + (lane & 15);
            int off = c * 32 + ((fslot ^ ((c >> 1) & 3)) << 3);
            Bh[ct] = *(const short8_t*)&lds[BHI_OFF + off];
            Bl[ct] = *(const short8_t*)&lds[BLO_OFF + off];
        }
#pragma unroll
        for (int rt = 0; rt < 2; ++rt)
#pragma unroll
            for (int ct = 0; ct < NCT; ++ct) {
                acc[rt][ct] = __builtin_amdgcn_mfma_f32_16x16x32_bf16(Ah[rt], Bh[ct], acc[rt][ct], 0, 0, 0);
                acc[rt][ct] = __builtin_amdgcn_mfma_f32_16x16x32_bf16(Ah[rt], Bl[ct], acc[rt][ct], 0, 0, 0);
                if (AMODE == 0)
                    acc[rt][ct] = __builtin_amdgcn_mfma_f32_16x16x32_bf16(Al[rt], Bh[ct], acc[rt][ct], 0, 0, 0);
            }
        __syncthreads();
    }

#pragma unroll
    for (int rt = 0; rt < 2; ++rt) {
#pragma unroll
        for (int reg = 0; reg < 4; ++reg) {
            int r = row0 + rbase + rt * 16 + (lane >> 4) * 4 + reg;
            if (ATTN) {
                float ps = 0.f, pd = 0.f;
#pragma unroll
                for (int ct = 0; ct < NCT; ++ct) {
                    int c = cbase + ct * 16 + (lane & 15);
                    ps += acc[rt][ct][reg] * att_src[c];
                    pd += acc[rt][ct][reg] * att_dst[c];
                }
#pragma unroll
                for (int off = 1; off < 16; off <<= 1) {
                    ps += __shfl_xor(ps, off);
                    pd += __shfl_xor(pd, off);
                }
                if (r < M && (lane & 15) == 0) {
                    int head = w >> 1;
                    a_srcO[r * 2 + head] = ps;
                    a_dstO[r * 2 + head] = pd;
                }
            }
            if (r >= M) continue;
#pragma unroll
            for (int ct = 0; ct < NCT; ++ct) {
                int c = cbase + ct * 16 + (lane & 15);
                float v = acc[rt][ct][reg];
                if (OUTBF16) {
                    if (bias) v += bias[c];
                    ((unsigned short*)Cout)[(size_t)r * 128 + c] = f2bf(v);
                } else {
                    if (c < Nact) {
                        if (bias) v += bias[c];
                        ((float*)Cout)[(size_t)r * ldc + c] = v;
                    }
                }
            }
        }
    }
#undef LOADA_
#undef LOADB_
}

// ================= merged prep/csr kernels =================
__global__ __launch_bounds__(256) void prep1_kernel(
    const int* __restrict__ ei, int* __restrict__ cnt,
    const float* __restrict__ W0, const float* __restrict__ W1,
    const float* __restrict__ W_out, const float* __restrict__ b_feat,
    unsigned short* BT0hi, unsigned short* BT0lo,
    unsigned short* BTbhi, unsigned short* BTblo,
    unsigned short* BT1hi, unsigned short* BT1lo,
    unsigned short* BTohi, unsigned short* BTolo,
    float* __restrict__ cvec)
{
    __shared__ int h[NBUCK];
    int bid = blockIdx.x;
    if (bid < NPBLK) { part_count_body(bid, h, ei, cnt); return; }
    bid -= NPBLK;
    if (bid < 128) { bsplit_body(bid, W0, 128, 40, 128, BT0hi, BT0lo, 320, 0, 64); return; }
    bid -= 128;
    if (bid < 128) { bsplit_body(bid, W0 + 40 * 128, 128, 128, 128, BTbhi, BTblo, 128, 0, 128); return; }
    bid -= 128;
    if (bid < 128) { bsplit_body(bid, W1, 128, 128, 128, BT1hi, BT1lo, 128, 0, 128); return; }
    bid -= 128;
    if (bid < 128) { bsplit_body(bid, W_out, 40, 128, 40, BTohi, BTolo, 128, 0, 128); return; }
    cvec_body(b_feat, W0, cvec);
}

__global__ __launch_bounds__(256) void prep2_kernel(
    const int* __restrict__ cnt, int* __restrict__ pbase, int* __restrict__ bbase,
    const float* __restrict__ W_feat,
    const unsigned short* BTbhi, const unsigned short* BTblo,
    float* __restrict__ Wc)
{
    __shared__ __align__(16) unsigned short smem[12288];
    if (blockIdx.x == 0) {
        part_scan_body((int*)smem, cnt, pbase, bbase);
    } else {
        gemm_body<0, 0, 0, 4>(blockIdx.x - 1, smem,
            W_feat, 128, 128, 128, nullptr, 0, 0, 256,
            BTbhi, BTblo, 128, 128, Wc, 128, 128, nullptr,
            nullptr, nullptr, nullptr, nullptr);
    }
}

__global__ __launch_bounds__(256) void prep3_kernel(
    const int* __restrict__ ei, const int* __restrict__ pbase,
    unsigned int* __restrict__ bbuf,
    const float* __restrict__ Wc,
    unsigned short* BT0hi, unsigned short* BT0lo)
{
    __shared__ int lcur[NBUCK];
    if (blockIdx.x < NPBLK) {
        part_scatter_body(blockIdx.x, lcur, ei, pbase, bbuf);
    } else {
        bsplit_body(blockIdx.x - NPBLK, Wc, 128, 256, 128, BT0hi, BT0lo, 320, 64, 256);
    }
}

__global__ __launch_bounds__(256) void csr_gemm_kernel(
    const unsigned int* __restrict__ bbuf, const int* __restrict__ bbase,
    int* __restrict__ row_ptr, int* __restrict__ colbuf,
    const float* __restrict__ logits, const float* __restrict__ features,
    const unsigned short* BT0hi, const unsigned short* BT0lo,
    unsigned short* __restrict__ hbuf, const float* __restrict__ cvec,
    const float* __restrict__ att_src0, const float* __restrict__ att_dst0,
    float* __restrict__ a_srcb, float* __restrict__ a_dstb)
{
    __shared__ __align__(16) unsigned short smem[10240];
    if (blockIdx.x < NBUCK) {
        csr_build_body(blockIdx.x, (int*)smem, bbuf, bbase, row_ptr, colbuf);
    } else {
        gemm_body<1, 2, 1, 4>(blockIdx.x - NBUCK, smem,
            logits, 40, 40, 64, features, 256, 256, NN,
            BT0hi, BT0lo, 320, 320, hbuf, 128, 128, cvec,
            att_src0, att_dst0, a_srcb, a_dstb);
    }
}

// ========== FUSED: CSR gather-agg (64 nodes/block) -> K=128 MFMA GEMM ==========
// Phase 1: each wave aggs 16 nodes (2/iter x 8 iters), writing bf16 results
//          directly into the A-staging LDS (swizzle-matched to MFMA fragments).
// Phase 2: B-only 4-step K=128 GEMM; A fully LDS-resident.
// RELU/bias apply to the agg output (pre-GEMM). ATTN epilogue -> a_srcO/a_dstO.
template <int RELU, int ATTN, int NCT, int OUTBF16>
__global__ __launch_bounds__(256) void agg_gemm_kernel(
    const int* __restrict__ row_ptr, const int* __restrict__ col,
    const float* __restrict__ a_src, const float* __restrict__ a_dst,
    const unsigned short* __restrict__ hb, const float* __restrict__ bias,
    const unsigned short* __restrict__ BThi, const unsigned short* __restrict__ BTlo,
    int bstride,
    void* __restrict__ Cout, int ldc, int Nact, const float* __restrict__ obias,
    const float* __restrict__ att_src, const float* __restrict__ att_dst,
    float* __restrict__ a_srcO, float* __restrict__ a_dstO)
{
    constexpr int ASZ = 8192;                       // 4 k-steps x 64 rows x 32 shorts
    constexpr int BHALF = (NCT == 4) ? 4096 : 2048;
    constexpr int BHI_OFF = ASZ;
    constexpr int BLO_OFF = ASZ + BHALF;
    __shared__ __align__(16) unsigned short lds[ASZ + 2 * BHALF];

    const int t = threadIdx.x;
    const int wv = t >> 6, lane = t & 63;
    const int hl = lane >> 5;
    const int l5 = lane & 31;
    const int hch = l5 >> 4;
    const int row0 = blockIdx.x * 64;
    const uint2* h4 = (const uint2*)hb;

    // A-write address components (constant per lane)
    const int kstepA = l5 >> 3;
    const int slotA  = (l5 >> 1) & 3;
    const int halfA  = l5 & 1;

    // ---------- phase 1: aggregation into LDS ----------
    for (int it = 0; it < 8; ++it) {
        int r = wv * 16 + it * 2 + hl;
        int n = row0 + r;
        bool ok = (n < NN);

        float a0 = 0.f, a1 = 0.f, a2 = 0.f, a3 = 0.f, den = 1.f, adh = 0.f;
        int rs = 0, re = 0;
        if (ok) {
            float2 ad2 = ((const float2*)a_dst)[n];
            adh = hch ? ad2.y : ad2.x;
            float2 as2 = ((const float2*)a_src)[n];
            float e0 = (hch ? as2.y : as2.x) + adh;
            e0 = e0 > 0.f ? e0 : 0.2f * e0;
            float w = __expf(e0);
            uint2 hv = h4[(size_t)n * 32 + l5];
            a0 = w * u2f(hv.x << 16);
            a1 = w * u2f(hv.x & 0xFFFF0000u);
            a2 = w * u2f(hv.y << 16);
            a3 = w * u2f(hv.y & 0xFFFF0000u);
            den = w;
            rs = row_ptr[n];
            re = row_ptr[n + 1];
        }
        int deg = re - rs;
        int degO = __shfl(deg, lane ^ 32);
        int degm = deg > degO ? deg : degO;
        int nbm = (degm + 15) >> 4;

        for (int bi = 0; bi < nbm; ++bi) {
            int base = rs + bi * 16;
            int cnt = re - base;
            cnt = cnt < 0 ? 0 : (cnt > 16 ? 16 : cnt);
            int cntO = __shfl(cnt, lane ^ 32);
            int cntm = cnt > cntO ? cnt : cntO;
            int j16 = l5 & 15;
            int sL = 0;
            float wL = 0.f;
            if (j16 < cnt) {
                sL = col[base + j16];
                float2 as = ((const float2*)a_src)[sL];
                float tt = (hch ? as.y : as.x) + adh;
                tt = tt > 0.f ? tt : 0.2f * tt;
                wL = __expf(tt);
            }
            const int sb = hl << 5;
            const int wb = sb + (hch << 4);
            int i = 0;
            for (; i + 8 <= cntm; i += 8) {
                int s[8]; uint2 g[8]; float ws[8];
#pragma unroll
                for (int j = 0; j < 8; ++j) s[j] = __shfl(sL, sb + i + j);
#pragma unroll
                for (int j = 0; j < 8; ++j) g[j] = h4[(size_t)s[j] * 32 + l5];
#pragma unroll
                for (int j = 0; j < 8; ++j) ws[j] = __shfl(wL, wb + i + j);
#pragma unroll
                for (int j = 0; j < 8; ++j) {
                    a0 += ws[j] * u2f(g[j].x << 16);
                    a1 += ws[j] * u2f(g[j].x & 0xFFFF0000u);
                    a2 += ws[j] * u2f(g[j].y << 16);
                    a3 += ws[j] * u2f(g[j].y & 0xFFFF0000u);
                    den += ws[j];
                }
            }
            for (; i + 4 <= cntm; i += 4) {
                int s[4]; uint2 g[4]; float ws[4];
#pragma unroll
                for (int j = 0; j < 4; ++j) s[j] = __shfl(sL, sb + i + j);
#pragma unroll
                for (int j = 0; j < 4; ++j) g[j] = h4[(size_t)s[j] * 32 + l5];
#pragma unroll
                for (int j = 0; j < 4; ++j) ws[j] = __shfl(wL, wb + i + j);
#pragma unroll
                for (int j = 0; j < 4; ++j) {
                    a0 += ws[j] * u2f(g[j].x << 16);
                    a1 += ws[j] * u2f(g[j].x & 0xFFFF0000u);
                    a2 += ws[j] * u2f(g[j].y << 16);
                    a3 += ws[j] * u2f(g[j].y & 0xFFFF0000u);
                    den += ws[j];
                }
            }
            for (; i < cntm; ++i) {
                int s = __shfl(sL, sb + i);
                float ws = __shfl(wL, wb + i);
                uint2 g = h4[(size_t)s * 32 + l5];
                a0 += ws * u2f(g.x << 16);
                a1 += ws * u2f(g.x & 0xFFFF0000u);
                a2 += ws * u2f(g.y << 16);
                a3 += ws * u2f(g.y & 0xFFFF0000u);
                den += ws;
            }
        }
        float o0 = 0.f, o1 = 0.f, o2 = 0.f, o3 = 0.f;
        if (ok) {
            float inv = 1.f / (den + 1e-16f);
            float4 b4 = ((const float4*)bias)[l5];
            o0 = a0 * inv + b4.x;
            o1 = a1 * inv + b4.y;
            o2 = a2 * inv + b4.z;
            o3 = a3 * inv + b4.w;
            if (RELU) {
                o0 = fmaxf(o0, 0.f); o1 = fmaxf(o1, 0.f);
                o2 = fmaxf(o2, 0.f); o3 = fmaxf(o3, 0.f);
            }
        }
        short4_t pk = {(short)f2bf(o0), (short)f2bf(o1), (short)f2bf(o2), (short)f2bf(o3)};
        int ao = kstepA * 2048 + r * 32 + ((slotA ^ ((r >> 1) & 3)) << 3) + halfA * 4;
        *(short4_t*)&lds[ao] = pk;
    }
    __syncthreads();

    // ---------- phase 2: K=128 GEMM, A LDS-resident ----------
    const int rbase = (wv & 1) * 32;
    const int cbase = (NCT == 4) ? (wv >> 1) * 64 : (wv >> 1) * 32;

    f32x4 acc[2][NCT];
#pragma unroll
    for (int i = 0; i < 2; ++i)
#pragma unroll
        for (int j = 0; j < NCT; ++j) acc[i][j] = (f32x4){0.f, 0.f, 0.f, 0.f};

    const int bc0 = t >> 2,         bs0 = t & 3;
    const int bc1 = (t + 256) >> 2, bs1 = (t + 256) & 3;
    const int bo0 = bc0 * 32 + ((bs0 ^ ((bc0 >> 1) & 3)) << 3);
    const int bo1 = bc1 * 32 + ((bs1 ^ ((bc1 >> 1) & 3)) << 3);

    short8_t rbh0, rbl0, rbh1, rbl1;
#define LOADB2_(k0_) {                                                    \
        size_t g0_ = (size_t)bc0 * bstride + (k0_) + bs0 * 8;             \
        rbh0 = *(const short8_t*)&BThi[g0_];                              \
        rbl0 = *(const short8_t*)&BTlo[g0_];                              \
        if (NCT == 4) {                                                   \
            size_t g1_ = (size_t)bc1 * bstride + (k0_) + bs1 * 8;         \
            rbh1 = *(const short8_t*)&BThi[g1_];                          \
            rbl1 = *(const short8_t*)&BTlo[g1_];                          \
        }                                                                 \
    }
    LOADB2_(0);
    for (int k0 = 0; k0 < 128; k0 += 32) {
        *(short8_t*)&lds[BHI_OFF + bo0] = rbh0;
        *(short8_t*)&lds[BLO_OFF + bo0] = rbl0;
        if (NCT == 4) {
            *(short8_t*)&lds[BHI_OFF + bo1] = rbh1;
            *(short8_t*)&lds[BLO_OFF + bo1] = rbl1;
        }
        __syncthreads();
        if (k0 + 32 < 128) LOADB2_(k0 + 32);

        short8_t Ah[2], Bh[NCT], Bl[NCT];
        const int fslot = lane >> 4;
        const int abase = (k0 >> 5) * 2048;
#pragma unroll
        for (int rt = 0; rt < 2; ++rt) {
            int r = rbase + rt * 16 + (lane & 15);
            Ah[rt] = *(const short8_t*)&lds[abase + r * 32 + ((fslot ^ ((r >> 1) & 3)) << 3)];
        }
#pragma unroll
        for (int ct = 0; ct < NCT; ++ct) {
            int c = cbase + ct * 16 + (lane & 15);
            int off = c * 32 + ((fslot ^ ((c >> 1) & 3)) << 3);
            Bh[ct] = *(const short8_t*)&lds[BHI_OFF + off];
            Bl[ct] = *(const short8_t*)&lds[BLO_OFF + off];
        }
#pragma unroll
        for (int rt = 0; rt < 2; ++rt)
#pragma unroll
            for (int ct = 0; ct < NCT; ++ct) {
                acc[rt][ct] = __builtin_amdgcn_mfma_f32_16x16x32_bf16(Ah[rt], Bh[ct], acc[rt][ct], 0, 0, 0);
                acc[rt][ct] = __builtin_amdgcn_mfma_f32_16x16x32_bf16(Ah[rt], Bl[ct], acc[rt][ct], 0, 0, 0);
            }
        __syncthreads();
    }
#undef LOADB2_

    // ---------- epilogue ----------
#pragma unroll
    for (int rt = 0; rt < 2; ++rt) {
#pragma unroll
        for (int reg = 0; reg < 4; ++reg) {
            int r = row0 + rbase + rt * 16 + (lane >> 4) * 4 + reg;
            if (ATTN) {
                float ps = 0.f, pd = 0.f;
#pragma unroll
                for (int ct = 0; ct < NCT; ++ct) {
                    int c = cbase + ct * 16 + (lane & 15);
                    ps += acc[rt][ct][reg] * att_src[c];
                    pd += acc[rt][ct][reg] * att_dst[c];
                }
#pragma unroll
                for (int off = 1; off < 16; off <<= 1) {
                    ps += __shfl_xor(ps, off);
                    pd += __shfl_xor(pd, off);
                }
                if (r < NN && (lane & 15) == 0) {
                    int head = wv >> 1;
                    a_srcO[r * 2 + head] = ps;
                    a_dstO[r * 2 + head] = pd;
                }
            }
            if (r >= NN) continue;
#pragma unroll
            for (int ct = 0; ct < NCT; ++ct) {
                int c = cbase + ct * 16 + (lane & 15);
                float v = acc[rt][ct][reg];
                if (OUTBF16) {
                    if (obias) v += obias[c];
                    ((unsigned short*)Cout)[(size_t)r * 128 + c] = f2bf(v);
                } else {
                    if (c < Nact) {
                        if (obias) v += obias[c];
                        ((float*)Cout)[(size_t)r * ldc + c] = v;
                    }
                }
            }
        }
    }
}

extern "C" void kernel_launch(void* const* d_in, const int* in_sizes, int n_in,
                              void* d_out, int out_size, void* d_ws, size_t ws_size,
                              hipStream_t stream) {
    const float* logits   = (const float*)d_in[0];
    const float* features = (const float*)d_in[1];
    const int*   ei       = (const int*)d_in[2];
    const float* W_feat   = (const float*)d_in[3];
    const float* b_feat   = (const float*)d_in[4];
    const float* W0       = (const float*)d_in[5];
    const float* att_src0 = (const float*)d_in[6];
    const float* att_dst0 = (const float*)d_in[7];
    const float* bias0    = (const float*)d_in[8];
    const float* W1       = (const float*)d_in[9];
    const float* att_src1 = (const float*)d_in[10];
    const float* att_dst1 = (const float*)d_in[11];
    const float* bias1    = (const float*)d_in[12];
    const float* W_out    = (const float*)d_in[13];
    const float* b_out    = (const float*)d_in[14];
    float* out = (float*)d_out;

    float* reg0   = (float*)d_ws;                       // NN*128 region (bbuf then hbuf2)
    float* a_srcb = reg0 + (size_t)NN * 128;            // NN*2 (layer0)
    float* a_dstb = a_srcb + (size_t)NN * 2;            // NN*2
    float* Wc     = a_dstb + (size_t)NN * 2;            // 256*128
    float* cvec   = Wc + 256 * 128;                     // 128
    unsigned short* hbuf = (unsigned short*)(cvec + 128);      // NN*128 bf16 (layer0 h)
    unsigned short* BT0hi = hbuf + (size_t)NN * 128;    // 128*320
    unsigned short* BT0lo = BT0hi + 128 * 320;
    unsigned short* BTbhi = BT0lo + 128 * 320;          // 128*128
    unsigned short* BTblo = BTbhi + 128 * 128;
    unsigned short* BT1hi = BTblo + 128 * 128;          // 128*128
    unsigned short* BT1lo = BT1hi + 128 * 128;
    unsigned short* BTohi = BT1lo + 128 * 128;          // 128*128
    unsigned short* BTolo = BTohi + 128 * 128;
    int* row_ptr = (int*)(BTolo + 128 * 128);           // NN+1
    int* colbuf  = row_ptr + NN + 1;                    // EE
    int* cnt     = colbuf + EE;                         // NPBLK*NBUCK
    int* pbase   = cnt + NPBLK * NBUCK;                 // NPBLK*NBUCK
    int* bbase   = pbase + NPBLK * NBUCK;               // NBUCK+1
    float* a_src1b = (float*)(bbase + NBUCK + 1);       // NN*2 (layer1)
    float* a_dst1b = a_src1b + (size_t)NN * 2;          // NN*2
    unsigned int* bbuf = (unsigned int*)reg0;           // EE u32 (dead after K4)
    unsigned short* hbuf2 = (unsigned short*)reg0;      // NN*128 bf16 (born after K4)

    dim3 blk(256);
    const int gemmGrid = (NN + 63) / 64;                // 1563

    // K1: part_count ∥ bsplit(W0a,W0b,W1,Wout) ∥ cvec
    prep1_kernel<<<dim3(NPBLK + 4 * 128 + 1), blk, 0, stream>>>(
        ei, cnt, W0, W1, W_out, b_feat,
        BT0hi, BT0lo, BTbhi, BTblo, BT1hi, BT1lo, BTohi, BTolo, cvec);

    // K2: part_scan ∥ Wc = W_feat @ W0b
    prep2_kernel<<<dim3(5), blk, 0, stream>>>(cnt, pbase, bbase, W_feat, BTbhi, BTblo, Wc);

    // K3: part_scatter ∥ bsplit(Wc)
    prep3_kernel<<<dim3(NPBLK + 128), blk, 0, stream>>>(ei, pbase, bbuf, Wc, BT0hi, BT0lo);

    // K4: csr_build ∥ layer-0 GEMM (input assembly + attn dots fused)
    csr_gemm_kernel<<<dim3(NBUCK + gemmGrid), blk, 0, stream>>>(
        bbuf, bbase, row_ptr, colbuf,
        logits, features, BT0hi, BT0lo, hbuf, cvec,
        att_src0, att_dst0, a_srcb, a_dstb);

    // K5: agg0 (bias0, relu) + layer-1 GEMM -> hbuf2, a_src1
    agg_gemm_kernel<1, 1, 4, 1><<<dim3(gemmGrid), blk, 0, stream>>>(
        row_ptr, colbuf, a_srcb, a_dstb, hbuf, bias0,
        BT1hi, BT1lo, 128,
        hbuf2, 128, 128, nullptr,
        att_src1, att_dst1, a_src1b, a_dst1b);

    // K6: agg1 (bias1) + output projection -> out
    agg_gemm_kernel<0, 0, 2, 0><<<dim3(gemmGrid), blk, 0, stream>>>(
        row_ptr, colbuf, a_src1b, a_dst1b, hbuf2, bias1,
        BTohi, BTolo, 128,
        out, 40, 40, b_out,
        nullptr, nullptr, nullptr, nullptr);
}

// Round 17
// 266.141 us; speedup vs baseline: 1.0892x; 1.0892x over previous
//
#include <hip/hip_runtime.h>

#define NN 100000
#define EE 1600000
#define NBUCK ((NN + 255) >> 8)        // 391
#define CHUNK 8192
#define NPBLK ((EE + CHUNK - 1) / CHUNK) // 196

typedef __attribute__((ext_vector_type(8))) short short8_t;
typedef __attribute__((ext_vector_type(4))) float f32x4;

static __device__ inline unsigned short f2bf(float f) {
    unsigned int u = __float_as_uint(f);
    u += 0x7FFFu + ((u >> 16) & 1u);
    return (unsigned short)(u >> 16);
}
static __device__ inline float bf2f(unsigned short h) {
    return __uint_as_float(((unsigned int)h) << 16);
}
static __device__ inline float u2f(unsigned int u) { return __uint_as_float(u); }

// ================= CSR bodies =================
static __device__ void part_count_body(int bid, int* h, const int* __restrict__ ei,
                                       int* __restrict__ cnt) {
    for (int i = threadIdx.x; i < NBUCK; i += 256) h[i] = 0;
    __syncthreads();
    int e0 = bid * CHUNK;
    int e1 = e0 + CHUNK; if (e1 > EE) e1 = EE;
    for (int e = e0 + threadIdx.x; e < e1; e += 256)
        atomicAdd(&h[ei[EE + e] >> 8], 1);
    __syncthreads();
    for (int i = threadIdx.x; i < NBUCK; i += 256)
        cnt[bid * NBUCK + i] = h[i];
}

static __device__ void part_scan_body(int* S, const int* __restrict__ cnt,
                                      int* __restrict__ base, int* __restrict__ bbase) {
    int* A = S;
    int* B = S + 512;
    int t = threadIdx.x;
    int totLoc[2];
#pragma unroll
    for (int q = 0; q < 2; ++q) {
        int idx = t + q * 256;
        int v = 0;
        if (idx < NBUCK)
            for (int k = 0; k < NPBLK; ++k) v += cnt[k * NBUCK + idx];
        totLoc[q] = v;
        A[idx] = v;
    }
    __syncthreads();
    int* src = A;
    int* dst = B;
    for (int off = 1; off < 512; off <<= 1) {
#pragma unroll
        for (int q = 0; q < 2; ++q) {
            int idx = t + q * 256;
            dst[idx] = src[idx] + (idx >= off ? src[idx - off] : 0);
        }
        __syncthreads();
        int* tmp = src; src = dst; dst = tmp;
    }
#pragma unroll
    for (int q = 0; q < 2; ++q) {
        int idx = t + q * 256;
        if (idx < NBUCK) {
            int excl = src[idx] - totLoc[q];
            bbase[idx] = excl;
            int run = excl;
            for (int k = 0; k < NPBLK; ++k) {
                base[k * NBUCK + idx] = run;
                run += cnt[k * NBUCK + idx];
            }
        }
    }
    if (t == 0) bbase[NBUCK] = EE;
}

static __device__ void part_scatter_body(int bid, int* lcur, const int* __restrict__ ei,
                                         const int* __restrict__ base,
                                         unsigned int* __restrict__ bbuf) {
    for (int i = threadIdx.x; i < NBUCK; i += 256)
        lcur[i] = base[bid * NBUCK + i];
    __syncthreads();
    int e0 = bid * CHUNK;
    int e1 = e0 + CHUNK; if (e1 > EE) e1 = EE;
    for (int e = e0 + threadIdx.x; e < e1; e += 256) {
        int s = ei[e], d = ei[EE + e];
        int pos = atomicAdd(&lcur[d >> 8], 1);
        bbuf[pos] = (unsigned int)s | ((unsigned int)(d & 255) << 24);
    }
}

static __device__ void csr_build_body(int b, int* S, const unsigned int* __restrict__ bbuf,
                                      const int* __restrict__ bbase,
                                      int* __restrict__ row_ptr, int* __restrict__ col) {
    int* hist = S;
    int* sc   = S + 256;
    int* lcur = S + 512;
    int t = threadIdx.x;
    int n0 = b << 8;
    int nCnt = NN - n0; if (nCnt > 256) nCnt = 256;
    int es = bbase[b], ee2 = bbase[b + 1];
    hist[t] = 0;
    __syncthreads();
    for (int i = es + t; i < ee2; i += 256)
        atomicAdd(&hist[bbuf[i] >> 24], 1);
    __syncthreads();
    int v = hist[t];
    sc[t] = v;
    __syncthreads();
    for (int off = 1; off < 256; off <<= 1) {
        int u = (t >= off) ? sc[t - off] : 0;
        __syncthreads();
        sc[t] += u;
        __syncthreads();
    }
    int excl = sc[t] - v;
    if (t < nCnt) row_ptr[n0 + t] = es + excl;
    if (b == 0 && t == 0) row_ptr[NN] = EE;
    lcur[t] = excl;
    __syncthreads();
    for (int i = es + t; i < ee2; i += 256) {
        unsigned int pk = bbuf[i];
        int lpos = atomicAdd(&lcur[pk >> 24], 1);
        col[es + lpos] = (int)(pk & 0x00FFFFFFu);
    }
}

// ================= weight prep bodies =================
static __device__ void bsplit_body(int col, const float* __restrict__ W, int ldw, int K, int N,
                                   unsigned short* __restrict__ BThi,
                                   unsigned short* __restrict__ BTlo,
                                   int stride, int koff, int KPseg) {
    int k = threadIdx.x;
    if (k >= KPseg) return;
    float v = (k < K && col < N) ? W[(size_t)k * ldw + col] : 0.f;
    unsigned short hi = f2bf(v);
    unsigned short lo = f2bf(v - bf2f(hi));
    BThi[(size_t)col * stride + koff + k] = hi;
    BTlo[(size_t)col * stride + koff + k] = lo;
}

static __device__ void cvec_body(const float* __restrict__ b_feat,
                                 const float* __restrict__ W0, float* __restrict__ cvec) {
    int j = threadIdx.x;
    if (j >= 128) return;
    float s = 0.f;
    for (int k = 0; k < 128; ++k) s += b_feat[k] * W0[(40 + k) * 128 + j];
    cvec[j] = s;
}

// ======== MFMA GEMM device body (R12 loop, AMODE per R14) ========
// AMODE 0: A f32, split hi/lo (3 products). 1: A bf16 (2). 2: A f32 single-round (2).
template <int OUTBF16, int AMODE, int ATTN, int NCT>
static __device__ void gemm_body(int gbid, unsigned short* lds,
    const void* __restrict__ A1v, int lda1, int K1, int KP1,
    const float* __restrict__ A2, int lda2, int K2,
    int M,
    const unsigned short* __restrict__ BThi, const unsigned short* __restrict__ BTlo,
    int bstride, int KPtot,
    void* __restrict__ Cout, int ldc, int Nact, const float* __restrict__ bias,
    const float* __restrict__ att_src, const float* __restrict__ att_dst,
    float* __restrict__ a_srcO, float* __restrict__ a_dstO)
{
    constexpr int ASZ = (AMODE == 0) ? 4096 : 2048;
    constexpr int BHALF = (NCT == 4) ? 4096 : 2048;
    constexpr int BHI_OFF = ASZ;
    constexpr int BLO_OFF = ASZ + BHALF;

    const int t = threadIdx.x;
    const int w = t >> 6, lane = t & 63;
    const int row0 = gbid * 64;
    const int rbase = (w & 1) * 32;
    const int cbase = (NCT == 4) ? (w >> 1) * 64 : (w >> 1) * 32;

    f32x4 acc[2][NCT];
#pragma unroll
    for (int i = 0; i < 2; ++i)
#pragma unroll
        for (int j = 0; j < NCT; ++j) acc[i][j] = (f32x4){0.f, 0.f, 0.f, 0.f};

    const int arow = t >> 2;
    const int aslot = t & 3;
    const bool rowok = (row0 + arow) < M;
    const int aoff = arow * 32 + (((aslot ^ ((arow >> 1) & 3))) << 3);

    const int bc0 = t >> 2,         bs0 = t & 3;
    const int bc1 = (t + 256) >> 2, bs1 = (t + 256) & 3;
    const int bo0 = bc0 * 32 + ((bs0 ^ ((bc0 >> 1) & 3)) << 3);
    const int bo1 = bc1 * 32 + ((bs1 ^ ((bc1 >> 1) & 3)) << 3);

    float ra[8];
    short8_t rab;
    short8_t rbh0, rbl0, rbh1, rbl1;
    const short8_t zz = {0, 0, 0, 0, 0, 0, 0, 0};

#define LOADB_(k0_) {                                                     \
        size_t g0_ = (size_t)bc0 * bstride + (k0_) + bs0 * 8;             \
        rbh0 = *(const short8_t*)&BThi[g0_];                              \
        rbl0 = *(const short8_t*)&BTlo[g0_];                              \
        if (NCT == 4) {                                                   \
            size_t g1_ = (size_t)bc1 * bstride + (k0_) + bs1 * 8;         \
            rbh1 = *(const short8_t*)&BThi[g1_];                          \
            rbl1 = *(const short8_t*)&BTlo[g1_];                          \
        }                                                                 \
    }

#define LOADA_(k0_) {                                                     \
        if (AMODE == 1) {                                                 \
            int gk = (k0_) + aslot * 8;                                   \
            if (rowok && gk + 8 <= K1) {                                  \
                const unsigned short* Ab =                                \
                    (const unsigned short*)A1v + (size_t)(row0 + arow) * lda1; \
                rab = *(const short8_t*)&Ab[gk];                          \
            } else rab = zz;                                              \
        } else {                                                          \
            const float* Asrc; int gk, Klim;                              \
            if ((k0_) < KP1) {                                            \
                Asrc = (const float*)A1v + (size_t)(row0 + arow) * lda1;  \
                gk = (k0_) + aslot * 8; Klim = K1;                        \
            } else {                                                      \
                Asrc = A2 + (size_t)(row0 + arow) * lda2;                 \
                gk = (k0_) - KP1 + aslot * 8; Klim = K2;                  \
            }                                                             \
            if (rowok && gk + 8 <= Klim) {                                \
                float4 v0 = *(const float4*)(Asrc + gk);                  \
                float4 v1 = *(const float4*)(Asrc + gk + 4);              \
                ra[0] = v0.x; ra[1] = v0.y; ra[2] = v0.z; ra[3] = v0.w;   \
                ra[4] = v1.x; ra[5] = v1.y; ra[6] = v1.z; ra[7] = v1.w;   \
            } else {                                                      \
                for (int j_ = 0; j_ < 8; ++j_) ra[j_] = 0.f;              \
            }                                                             \
        }                                                                 \
    }

    LOADA_(0);
    LOADB_(0);

    for (int k0 = 0; k0 < KPtot; k0 += 32) {
        if (AMODE == 1) {
            *(short8_t*)&lds[aoff] = rab;
        } else if (AMODE == 2) {
            short8_t vh;
#pragma unroll
            for (int j = 0; j < 8; ++j) vh[j] = (short)f2bf(ra[j]);
            *(short8_t*)&lds[aoff] = vh;
        } else {
            short8_t vh, vl;
#pragma unroll
            for (int j = 0; j < 8; ++j) {
                unsigned short hi = f2bf(ra[j]);
                vh[j] = (short)hi;
                vl[j] = (short)f2bf(ra[j] - bf2f(hi));
            }
            *(short8_t*)&lds[aoff] = vh;
            *(short8_t*)&lds[2048 + aoff] = vl;
        }
        *(short8_t*)&lds[BHI_OFF + bo0] = rbh0;
        *(short8_t*)&lds[BLO_OFF + bo0] = rbl0;
        if (NCT == 4) {
            *(short8_t*)&lds[BHI_OFF + bo1] = rbh1;
            *(short8_t*)&lds[BLO_OFF + bo1] = rbl1;
        }
        __syncthreads();

        if (k0 + 32 < KPtot) {
            LOADA_(k0 + 32);
            LOADB_(k0 + 32);
        }

        short8_t Ah[2], Al[2], Bh[NCT], Bl[NCT];
        const int fslot = lane >> 4;
#pragma unroll
        for (int rt = 0; rt < 2; ++rt) {
            int r = rbase + rt * 16 + (lane & 15);
            int off = r * 32 + ((fslot ^ ((r >> 1) & 3)) << 3);
            Ah[rt] = *(const short8_t*)&lds[off];
            if (AMODE == 0) Al[rt] = *(const short8_t*)&lds[2048 + off];
        }
#pragma unroll
        for (int ct = 0; ct < NCT; ++ct) {
            int c = cbase + ct * 16 + (lane & 15);
            int off = c * 32 + ((fslot ^ ((c >> 1) & 3)) << 3);
            Bh[ct] = *(const short8_t*)&lds[BHI_OFF + off];
            Bl[ct] = *(const short8_t*)&lds[BLO_OFF + off];
        }
#pragma unroll
        for (int rt = 0; rt < 2; ++rt)
#pragma unroll
            for (int ct = 0; ct < NCT; ++ct) {
                acc[rt][ct] = __builtin_amdgcn_mfma_f32_16x16x32_bf16(Ah[rt], Bh[ct], acc[rt][ct], 0, 0, 0);
                acc[rt][ct] = __builtin_amdgcn_mfma_f32_16x16x32_bf16(Ah[rt], Bl[ct], acc[rt][ct], 0, 0, 0);
                if (AMODE == 0)
                    acc[rt][ct] = __builtin_amdgcn_mfma_f32_16x16x32_bf16(Al[rt], Bh[ct], acc[rt][ct], 0, 0, 0);
            }
        __syncthreads();
    }

#pragma unroll
    for (int rt = 0; rt < 2; ++rt) {
#pragma unroll
        for (int reg = 0; reg < 4; ++reg) {
            int r = row0 + rbase + rt * 16 + (lane >> 4) * 4 + reg;
            if (ATTN) {
                float ps = 0.f, pd = 0.f;
#pragma unroll
                for (int ct = 0; ct < NCT; ++ct) {
                    int c = cbase + ct * 16 + (lane & 15);
                    ps += acc[rt][ct][reg] * att_src[c];
                    pd += acc[rt][ct][reg] * att_dst[c];
                }
#pragma unroll
                for (int off = 1; off < 16; off <<= 1) {
                    ps += __shfl_xor(ps, off);
                    pd += __shfl_xor(pd, off);
                }
                if (r < M && (lane & 15) == 0) {
                    int head = w >> 1;
                    a_srcO[r * 2 + head] = ps;
                    a_dstO[r * 2 + head] = pd;
                }
            }
            if (r >= M) continue;
#pragma unroll
            for (int ct = 0; ct < NCT; ++ct) {
                int c = cbase + ct * 16 + (lane & 15);
                float v = acc[rt][ct][reg];
                if (OUTBF16) {
                    if (bias) v += bias[c];
                    ((unsigned short*)Cout)[(size_t)r * 128 + c] = f2bf(v);
                } else {
                    if (c < Nact) {
                        if (bias) v += bias[c];
                        ((float*)Cout)[(size_t)r * ldc + c] = v;
                    }
                }
            }
        }
    }
#undef LOADA_
#undef LOADB_
}

// ================= merged kernels =================
__global__ __launch_bounds__(256) void prep1_kernel(
    const int* __restrict__ ei, int* __restrict__ cnt,
    const float* __restrict__ W0, const float* __restrict__ W1,
    const float* __restrict__ W_out, const float* __restrict__ b_feat,
    unsigned short* BT0hi, unsigned short* BT0lo,
    unsigned short* BTbhi, unsigned short* BTblo,
    unsigned short* BT1hi, unsigned short* BT1lo,
    unsigned short* BTohi, unsigned short* BTolo,
    float* __restrict__ cvec)
{
    __shared__ int h[NBUCK];
    int bid = blockIdx.x;
    if (bid < NPBLK) { part_count_body(bid, h, ei, cnt); return; }
    bid -= NPBLK;
    if (bid < 128) { bsplit_body(bid, W0, 128, 40, 128, BT0hi, BT0lo, 320, 0, 64); return; }
    bid -= 128;
    if (bid < 128) { bsplit_body(bid, W0 + 40 * 128, 128, 128, 128, BTbhi, BTblo, 128, 0, 128); return; }
    bid -= 128;
    if (bid < 128) { bsplit_body(bid, W1, 128, 128, 128, BT1hi, BT1lo, 128, 0, 128); return; }
    bid -= 128;
    if (bid < 128) { bsplit_body(bid, W_out, 40, 128, 40, BTohi, BTolo, 128, 0, 128); return; }
    cvec_body(b_feat, W0, cvec);
}

__global__ __launch_bounds__(256) void prep2_kernel(
    const int* __restrict__ cnt, int* __restrict__ pbase, int* __restrict__ bbase,
    const float* __restrict__ W_feat,
    const unsigned short* BTbhi, const unsigned short* BTblo,
    float* __restrict__ Wc)
{
    __shared__ __align__(16) unsigned short smem[12288];
    if (blockIdx.x == 0) {
        part_scan_body((int*)smem, cnt, pbase, bbase);
    } else {
        gemm_body<0, 0, 0, 4>(blockIdx.x - 1, smem,
            W_feat, 128, 128, 128, nullptr, 0, 0, 256,
            BTbhi, BTblo, 128, 128, Wc, 128, 128, nullptr,
            nullptr, nullptr, nullptr, nullptr);
    }
}

__global__ __launch_bounds__(256) void prep3_kernel(
    const int* __restrict__ ei, const int* __restrict__ pbase,
    unsigned int* __restrict__ bbuf,
    const float* __restrict__ Wc,
    unsigned short* BT0hi, unsigned short* BT0lo)
{
    __shared__ int lcur[NBUCK];
    if (blockIdx.x < NPBLK) {
        part_scatter_body(blockIdx.x, lcur, ei, pbase, bbuf);
    } else {
        bsplit_body(blockIdx.x - NPBLK, Wc, 128, 256, 128, BT0hi, BT0lo, 320, 64, 256);
    }
}

__global__ __launch_bounds__(256) void csr_gemm_kernel(
    const unsigned int* __restrict__ bbuf, const int* __restrict__ bbase,
    int* __restrict__ row_ptr, int* __restrict__ colbuf,
    const float* __restrict__ logits, const float* __restrict__ features,
    const unsigned short* BT0hi, const unsigned short* BT0lo,
    unsigned short* __restrict__ hbuf, const float* __restrict__ cvec,
    const float* __restrict__ att_src0, const float* __restrict__ att_dst0,
    float* __restrict__ a_srcb, float* __restrict__ a_dstb)
{
    __shared__ __align__(16) unsigned short smem[10240];
    if (blockIdx.x < NBUCK) {
        csr_build_body(blockIdx.x, (int*)smem, bbuf, bbase, row_ptr, colbuf);
    } else {
        gemm_body<1, 2, 1, 4>(blockIdx.x - NBUCK, smem,
            logits, 40, 40, 64, features, 256, 256, NN,
            BT0hi, BT0lo, 320, 320, hbuf, 128, 128, cvec,
            att_src0, att_dst0, a_srcb, a_dstb);
    }
}

template <int OUTBF16, int AMODE, int ATTN, int NCT>
__global__ __launch_bounds__(256) void gemm_kernel(
    const void* __restrict__ A1v, int lda1, int K1, int KP1,
    const float* __restrict__ A2, int lda2, int K2, int M,
    const unsigned short* __restrict__ BThi, const unsigned short* __restrict__ BTlo,
    int bstride, int KPtot,
    void* __restrict__ Cout, int ldc, int Nact, const float* __restrict__ bias,
    const float* __restrict__ att_src, const float* __restrict__ att_dst,
    float* __restrict__ a_srcO, float* __restrict__ a_dstO)
{
    __shared__ __align__(16) unsigned short lds[((AMODE == 0) ? 4096 : 2048) + ((NCT == 4) ? 8192 : 4096)];
    gemm_body<OUTBF16, AMODE, ATTN, NCT>(blockIdx.x, lds,
        A1v, lda1, K1, KP1, A2, lda2, K2, M, BThi, BTlo, bstride, KPtot,
        Cout, ldc, Nact, bias, att_src, att_dst, a_srcO, a_dstO);
}

// ========== fused GAT aggregation: 2 nodes per wave, CSR gather ==========
template <int RELU, int OUTBF16>
__global__ __launch_bounds__(256) void gat_agg_fused(
    const int* __restrict__ row_ptr, const int* __restrict__ col,
    const float* __restrict__ a_src, const float* __restrict__ a_dst,
    const unsigned short* __restrict__ hb,
    const float* __restrict__ bias, void* __restrict__ out)
{
    int wv = (blockIdx.x * 256 + threadIdx.x) >> 6;
    int lane = threadIdx.x & 63;
    int hl = lane >> 5;
    int l5 = lane & 31;
    int n = wv * 2 + hl;
    if (n >= NN) return;
    int hch = l5 >> 4;
    const uint2* h4 = (const uint2*)hb;

    float2 ad2 = ((const float2*)a_dst)[n];
    float adh = hch ? ad2.y : ad2.x;
    float2 as2 = ((const float2*)a_src)[n];
    float e0 = (hch ? as2.y : as2.x) + adh;
    e0 = e0 > 0.f ? e0 : 0.2f * e0;
    float w = __expf(e0);
    uint2 hv = h4[(size_t)n * 32 + l5];
    float a0 = w * u2f(hv.x << 16);
    float a1 = w * u2f(hv.x & 0xFFFF0000u);
    float a2 = w * u2f(hv.y << 16);
    float a3 = w * u2f(hv.y & 0xFFFF0000u);
    float den = w;

    int rs = row_ptr[n], re = row_ptr[n + 1];
    int deg = re - rs;
    int degO = __shfl(deg, lane ^ 32);
    int degm = deg > degO ? deg : degO;
    int nbm = (degm + 15) >> 4;

    for (int bi = 0; bi < nbm; ++bi) {
        int base = rs + bi * 16;
        int cnt = re - base;
        cnt = cnt < 0 ? 0 : (cnt > 16 ? 16 : cnt);
        int cntO = __shfl(cnt, lane ^ 32);
        int cntm = cnt > cntO ? cnt : cntO;
        int j16 = l5 & 15;
        int sL = 0;
        float wL = 0.f;
        if (j16 < cnt) {
            sL = col[base + j16];
            float2 as = ((const float2*)a_src)[sL];
            float tt = (hch ? as.y : as.x) + adh;
            tt = tt > 0.f ? tt : 0.2f * tt;
            wL = __expf(tt);
        }
        const int sb = hl << 5;
        const int wb = sb + (hch << 4);
        int i = 0;
        for (; i + 8 <= cntm; i += 8) {
            int s[8]; uint2 g[8]; float ws[8];
#pragma unroll
            for (int j = 0; j < 8; ++j) s[j] = __shfl(sL, sb + i + j);
#pragma unroll
            for (int j = 0; j < 8; ++j) g[j] = h4[(size_t)s[j] * 32 + l5];
#pragma unroll
            for (int j = 0; j < 8; ++j) ws[j] = __shfl(wL, wb + i + j);
#pragma unroll
            for (int j = 0; j < 8; ++j) {
                a0 += ws[j] * u2f(g[j].x << 16);
                a1 += ws[j] * u2f(g[j].x & 0xFFFF0000u);
                a2 += ws[j] * u2f(g[j].y << 16);
                a3 += ws[j] * u2f(g[j].y & 0xFFFF0000u);
                den += ws[j];
            }
        }
        for (; i + 4 <= cntm; i += 4) {
            int s[4]; uint2 g[4]; float ws[4];
#pragma unroll
            for (int j = 0; j < 4; ++j) s[j] = __shfl(sL, sb + i + j);
#pragma unroll
            for (int j = 0; j < 4; ++j) g[j] = h4[(size_t)s[j] * 32 + l5];
#pragma unroll
            for (int j = 0; j < 4; ++j) ws[j] = __shfl(wL, wb + i + j);
#pragma unroll
            for (int j = 0; j < 4; ++j) {
                a0 += ws[j] * u2f(g[j].x << 16);
                a1 += ws[j] * u2f(g[j].x & 0xFFFF0000u);
                a2 += ws[j] * u2f(g[j].y << 16);
                a3 += ws[j] * u2f(g[j].y & 0xFFFF0000u);
                den += ws[j];
            }
        }
        for (; i < cntm; ++i) {
            int s = __shfl(sL, sb + i);
            float ws = __shfl(wL, wb + i);
            uint2 g = h4[(size_t)s * 32 + l5];
            a0 += ws * u2f(g.x << 16);
            a1 += ws * u2f(g.x & 0xFFFF0000u);
            a2 += ws * u2f(g.y << 16);
            a3 += ws * u2f(g.y & 0xFFFF0000u);
            den += ws;
        }
    }
    float inv = 1.f / (den + 1e-16f);
    float4 b4 = ((const float4*)bias)[l5];
    float o0 = a0 * inv + b4.x;
    float o1 = a1 * inv + b4.y;
    float o2 = a2 * inv + b4.z;
    float o3 = a3 * inv + b4.w;
    if (RELU) {
        o0 = fmaxf(o0, 0.f); o1 = fmaxf(o1, 0.f);
        o2 = fmaxf(o2, 0.f); o3 = fmaxf(o3, 0.f);
    }
    if (OUTBF16) {
        uint2 pk;
        pk.x = (unsigned int)f2bf(o0) | ((unsigned int)f2bf(o1) << 16);
        pk.y = (unsigned int)f2bf(o2) | ((unsigned int)f2bf(o3) << 16);
        ((uint2*)out)[(size_t)n * 32 + l5] = pk;
    } else {
        ((float4*)out)[(size_t)n * 32 + l5] = make_float4(o0, o1, o2, o3);
    }
}

extern "C" void kernel_launch(void* const* d_in, const int* in_sizes, int n_in,
                              void* d_out, int out_size, void* d_ws, size_t ws_size,
                              hipStream_t stream) {
    const float* logits   = (const float*)d_in[0];
    const float* features = (const float*)d_in[1];
    const int*   ei       = (const int*)d_in[2];
    const float* W_feat   = (const float*)d_in[3];
    const float* b_feat   = (const float*)d_in[4];
    const float* W0       = (const float*)d_in[5];
    const float* att_src0 = (const float*)d_in[6];
    const float* att_dst0 = (const float*)d_in[7];
    const float* bias0    = (const float*)d_in[8];
    const float* W1       = (const float*)d_in[9];
    const float* att_src1 = (const float*)d_in[10];
    const float* att_dst1 = (const float*)d_in[11];
    const float* bias1    = (const float*)d_in[12];
    const float* W_out    = (const float*)d_in[13];
    const float* b_out    = (const float*)d_in[14];
    float* out = (float*)d_out;

    float* agg    = (float*)d_ws;                       // NN*128 f32 (bf16 views)
    float* a_srcb = agg + (size_t)NN * 128;             // NN*2
    float* a_dstb = a_srcb + (size_t)NN * 2;            // NN*2
    float* Wc     = a_dstb + (size_t)NN * 2;            // 256*128
    float* cvec   = Wc + 256 * 128;                     // 128
    unsigned short* hbuf = (unsigned short*)(cvec + 128);      // NN*128 bf16
    unsigned short* BT0hi = hbuf + (size_t)NN * 128;    // 128*320
    unsigned short* BT0lo = BT0hi + 128 * 320;
    unsigned short* BTbhi = BT0lo + 128 * 320;          // 128*128
    unsigned short* BTblo = BTbhi + 128 * 128;
    unsigned short* BT1hi = BTblo + 128 * 128;          // 128*128
    unsigned short* BT1lo = BT1hi + 128 * 128;
    unsigned short* BTohi = BT1lo + 128 * 128;          // 128*128
    unsigned short* BTolo = BTohi + 128 * 128;
    int* row_ptr = (int*)(BTolo + 128 * 128);           // NN+1
    int* colbuf  = row_ptr + NN + 1;                    // EE
    int* cnt     = colbuf + EE;                         // NPBLK*NBUCK
    int* pbase   = cnt + NPBLK * NBUCK;                 // NPBLK*NBUCK
    int* bbase   = pbase + NPBLK * NBUCK;               // NBUCK+1
    unsigned int* bbuf = (unsigned int*)agg;            // EE u32, aliases agg
    unsigned short* aggb = (unsigned short*)agg;        // bf16 view of agg region

    dim3 blk(256);
    const int gemmGrid = (NN + 63) / 64;                // 1563
    const int aggGrid = (NN / 2 + 3) / 4;

    // K1: part_count ∥ bsplit(W0a,W0b,W1,Wout) ∥ cvec
    prep1_kernel<<<dim3(NPBLK + 4 * 128 + 1), blk, 0, stream>>>(
        ei, cnt, W0, W1, W_out, b_feat,
        BT0hi, BT0lo, BTbhi, BTblo, BT1hi, BT1lo, BTohi, BTolo, cvec);

    // K2: part_scan ∥ Wc = W_feat @ W0b
    prep2_kernel<<<dim3(5), blk, 0, stream>>>(cnt, pbase, bbase, W_feat, BTbhi, BTblo, Wc);

    // K3: part_scatter ∥ bsplit(Wc)
    prep3_kernel<<<dim3(NPBLK + 128), blk, 0, stream>>>(ei, pbase, bbuf, Wc, BT0hi, BT0lo);

    // K4: csr_build ∥ GAT layer-0 GEMM (fused input assembly + attn dots)
    csr_gemm_kernel<<<dim3(NBUCK + gemmGrid), blk, 0, stream>>>(
        bbuf, bbase, row_ptr, colbuf,
        logits, features, BT0hi, BT0lo, hbuf, cvec,
        att_src0, att_dst0, a_srcb, a_dstb);

    gat_agg_fused<1, 1><<<dim3(aggGrid), blk, 0, stream>>>(
        row_ptr, colbuf, a_srcb, a_dstb, hbuf, bias0, aggb);

    // GAT layer 1 (bf16 A direct, attn dots fused)
    gemm_kernel<1, 1, 1, 4><<<dim3(gemmGrid), blk, 0, stream>>>(
        aggb, 128, 128, 128, nullptr, 0, 0, NN,
        BT1hi, BT1lo, 128, 128, hbuf, 128, 128, nullptr,
        att_src1, att_dst1, a_srcb, a_dstb);
    gat_agg_fused<0, 1><<<dim3(aggGrid), blk, 0, stream>>>(
        row_ptr, colbuf, a_srcb, a_dstb, hbuf, bias1, aggb);

    // output projection (bf16 A, BN=64, 40 used)
    gemm_kernel<0, 1, 0, 2><<<dim3(gemmGrid), blk, 0, stream>>>(
        aggb, 128, 128, 128, nullptr, 0, 0, NN,
        BTohi, BTolo, 128, 128, out, 40, 40, b_out,
        nullptr, nullptr, nullptr, nullptr);
}